// Round 1
// baseline (161.115 us; speedup 1.0000x reference)
//
#include <hip/hip_runtime.h>

// Problem constants: B=8, C=64, H=W=64, CI=32, N=4096 pixels, M=1024 pooled.
#define OFF_A    0         // a[b][n]            : 32768 floats
#define OFF_PSI  32768     // psi_pool[b][m][i]  : 262144
#define OFF_BB   294912    // bb[b][m]           : 8192
#define OFF_RANK 303104    // rank[b][m] (int)   : 8192
#define OFF_SBB  311296    // sorted bb[b][k]    : 8192
#define OFF_S1   319488    // S1[b][k<=1024][i]  : 262400
#define OFF_S2   581888    // S2[b][k<=1024][i]  : 262400
#define OFF_KK   844288    // k[b][n] (int)      : 32768
#define OFF_G    877056    // Gram 32x32         : 1024
#define OFF_SV   878080    // sum y              : 32
#define OFF_AW   878112    // A[o]*Ww[o][i]      : 2048
#define OFF_D    880160    // D[o]               : 64
// total 880224 floats = 3.52 MB of d_ws

// Kernel A: blocks [0,1024): fused phi/psi 1x1-conv + 2x2 maxpool; stores
// psi_pool and bb = w2 . phi_pool (shuffle-reduced over the 32 channel lanes).
// Blocks [1024,1152): theta path collapsed: a[b,n] = x[b,:,n].tw_eff + tb_eff.
__global__ __launch_bounds__(256) void kA(
    const float* __restrict__ x, const float* __restrict__ theta_w,
    const float* __restrict__ theta_b, const float* __restrict__ phi_w,
    const float* __restrict__ phi_b, const float* __restrict__ psi_w,
    const float* __restrict__ psi_b, const float* __restrict__ cp_w,
    float* ws)
{
    __shared__ float sm[4160];   // 2 x (32 rows x 65 padded) weight tiles
    int tid = threadIdx.x;
    int bid = blockIdx.x;
    if (bid < 1024) {
        for (int e = tid; e < 2048; e += 256) {
            int i = e >> 6, c = e & 63;
            sm[i*65 + c]        = phi_w[e];
            sm[2080 + i*65 + c] = psi_w[e];
        }
        __syncthreads();
        int t = (bid << 8) + tid;
        int i = t & 31;
        int m = (t >> 5) & 1023;
        int b = t >> 15;
        int ph = m >> 5, pw = m & 31;
        const float* xb = x + b*262144 + ph*128 + pw*2;
        const float* rp = sm + i*65;          // bank (i+c)%32: conflict-free
        const float* rs = sm + 2080 + i*65;
        float p0=0,p1=0,p2=0,p3=0,s0=0,s1=0,s2=0,s3=0;
        #pragma unroll 8
        for (int c = 0; c < 64; ++c) {
            float2 xa = *(const float2*)(xb + c*4096);
            float2 xc = *(const float2*)(xb + c*4096 + 64);
            float wp = rp[c], wv = rs[c];
            p0 += xa.x*wp; p1 += xa.y*wp; p2 += xc.x*wp; p3 += xc.y*wp;
            s0 += xa.x*wv; s1 += xa.y*wv; s2 += xc.x*wv; s3 += xc.y*wv;
        }
        float pv = fmaxf(fmaxf(p0,p1), fmaxf(p2,p3)) + phi_b[i];
        float sv = fmaxf(fmaxf(s0,s1), fmaxf(s2,s3)) + psi_b[i];
        ws[OFF_PSI + (b<<15) + (m<<5) + i] = sv;
        float v = pv * cp_w[32 + i];
        v += __shfl_xor(v, 16, 32);
        v += __shfl_xor(v,  8, 32);
        v += __shfl_xor(v,  4, 32);
        v += __shfl_xor(v,  2, 32);
        v += __shfl_xor(v,  1, 32);
        if (i == 0) ws[OFF_BB + (b<<10) + m] = v;
    } else {
        if (tid < 64) {
            float s = 0;
            for (int i = 0; i < 32; ++i) s += cp_w[i]*theta_w[i*64 + tid];
            sm[tid] = s;
        } else if (tid == 64) {
            float s = 0;
            for (int i = 0; i < 32; ++i) s += cp_w[i]*theta_b[i];
            sm[64] = s;
        }
        __syncthreads();
        int t = ((bid - 1024) << 8) + tid;
        int n = t & 4095, b = t >> 12;
        const float* xb = x + b*262144 + n;
        float acc = sm[64];
        #pragma unroll 8
        for (int c = 0; c < 64; ++c) acc += xb[c*4096]*sm[c];
        ws[OFF_A + t] = acc;
    }
}

// Rank of each bb within its batch (descending, index tiebreak) by counting.
__global__ __launch_bounds__(256) void kRank(float* ws)
{
    __shared__ float sb[1024];
    int tid = threadIdx.x;
    int b = blockIdx.x >> 5, chunk = blockIdx.x & 31;
    const float* bb = ws + OFF_BB + (b<<10);
    for (int e = tid; e < 1024; e += 256) sb[e] = bb[e];
    __syncthreads();
    int ml = tid >> 3, jl = tid & 7;
    int m = (chunk<<5) + ml;
    float v = sb[m];
    int cnt = 0;
    for (int s = 0; s < 128; ++s) {
        int j = jl + (s<<3);          // j = jl mod 8: bank-conflict-free
        float u = sb[j];
        cnt += (u > v || (u == v && j < m)) ? 1 : 0;
    }
    cnt += __shfl_xor(cnt, 1, 8);
    cnt += __shfl_xor(cnt, 2, 8);
    cnt += __shfl_xor(cnt, 4, 8);
    if (jl == 0) ((int*)ws)[OFF_RANK + (b<<10) + m] = cnt;
}

// Scatter into sorted order + prefix sums S1 (psi) and S2 (bb*psi). 1 block/batch.
__global__ __launch_bounds__(1024) void kPrefix(float* ws)
{
    __shared__ float ssort[1024];
    __shared__ int   sperm[1024];
    __shared__ float sc1[1024];
    __shared__ float sc2[1024];
    int tid = threadIdx.x;
    int b = blockIdx.x;
    float v = ws[OFF_BB + (b<<10) + tid];
    int r = ((const int*)ws)[OFF_RANK + (b<<10) + tid];
    ssort[r] = v; sperm[r] = tid;
    __syncthreads();
    ws[OFF_SBB + (b<<10) + tid] = ssort[tid];
    int i = tid & 31, ch = tid >> 5;     // 32 chunks x 32 elements
    const float* psi = ws + OFF_PSI + (b<<15);
    int j0 = ch << 5;
    float s1 = 0, s2 = 0;
    for (int j = 0; j < 32; ++j) {
        int jj = j0 + j;
        float p = psi[(sperm[jj]<<5) + i];
        s1 += p; s2 += ssort[jj]*p;
    }
    sc1[(ch<<5)+i] = s1; sc2[(ch<<5)+i] = s2;
    __syncthreads();
    if (tid < 32) {
        float run = 0;
        for (int c = 0; c < 32; ++c) { float t = sc1[(c<<5)+tid]; sc1[(c<<5)+tid] = run; run += t; }
    } else if (tid < 64) {
        int i2 = tid - 32;
        float run = 0;
        for (int c = 0; c < 32; ++c) { float t = sc2[(c<<5)+i2]; sc2[(c<<5)+i2] = run; run += t; }
    }
    __syncthreads();
    float run1 = sc1[(ch<<5)+i], run2 = sc2[(ch<<5)+i];
    float* S1 = ws + OFF_S1 + b*1025*32;
    float* S2 = ws + OFF_S2 + b*1025*32;
    if (tid < 32) { S1[tid] = 0.0f; S2[tid] = 0.0f; }
    for (int j = 0; j < 32; ++j) {
        int jj = j0 + j;
        float p = psi[(sperm[jj]<<5) + i];
        run1 += p; run2 += ssort[jj]*p;
        S1[((jj+1)<<5) + i] = run1;
        S2[((jj+1)<<5) + i] = run2;
    }
}

// Per-tile: binary-search k_n, reconstruct y tile in LDS, accumulate global
// Gram G += y y^T and svec += y via atomics. Stores k_n for the final kernel.
__global__ __launch_bounds__(256) void kGram(float* ws)
{
    __shared__ float ssbb[1024];
    __shared__ float sy[4096];    // 128 n x 32 i
    __shared__ float sa[128];
    __shared__ int   sk[128];
    int tid = threadIdx.x;
    int b = blockIdx.x >> 5;
    int n0 = (blockIdx.x & 31) << 7;
    const float* sbbg = ws + OFF_SBB + (b<<10);
    for (int e = tid; e < 1024; e += 256) ssbb[e] = sbbg[e];
    __syncthreads();
    if (tid < 128) {
        int n = n0 + tid;
        float av = ws[OFF_A + (b<<12) + n];
        float t = -av;
        int lo = 0, hi = 1024;
        while (lo < hi) { int mid = (lo+hi)>>1; if (ssbb[mid] > t) lo = mid+1; else hi = mid; }
        sa[tid] = av; sk[tid] = lo;
        ((int*)ws)[OFF_KK + (b<<12) + n] = lo;
    }
    __syncthreads();
    const float* S1 = ws + OFF_S1 + b*1025*32;
    const float* S2 = ws + OFF_S2 + b*1025*32;
    for (int e = tid; e < 4096; e += 256) {
        int nl = e >> 5, i = e & 31;
        int base = (sk[nl]<<5) + i;
        sy[e] = (sa[nl]*S1[base] + S2[base]) * (1.0f/1024.0f);
    }
    __syncthreads();
    int i = tid >> 3, j0 = (tid & 7) << 2;
    float4 acc = make_float4(0.f,0.f,0.f,0.f);
    for (int s = 0; s < 128; ++s) {
        float  yi = sy[(s<<5) + i];
        float4 yj = *(const float4*)&sy[(s<<5) + j0];
        acc.x += yi*yj.x; acc.y += yi*yj.y; acc.z += yi*yj.z; acc.w += yi*yj.w;
    }
    float* G = ws + OFF_G;
    atomicAdd(&G[(i<<5)+j0+0], acc.x);
    atomicAdd(&G[(i<<5)+j0+1], acc.y);
    atomicAdd(&G[(i<<5)+j0+2], acc.z);
    atomicAdd(&G[(i<<5)+j0+3], acc.w);
    if (tid < 32) {
        float sv = 0;
        for (int s = 0; s < 128; ++s) sv += sy[(s<<5) + tid];
        atomicAdd(&ws[OFF_SV + tid], sv);
    }
}

// Closed-form BN: mu/var per o from Gram + svec; emit Aw[o][i]=A*Ww, D[o].
__global__ __launch_bounds__(256) void kStats(
    const float* __restrict__ Ww, const float* __restrict__ Wb,
    const float* __restrict__ gamma, const float* __restrict__ beta,
    float* ws)
{
    __shared__ float sW[32];
    __shared__ float red[4];
    __shared__ float sLin[32];
    __shared__ float sAD[2];
    int tid = threadIdx.x;
    int o = blockIdx.x;
    if (tid < 32) sW[tid] = Ww[o*33 + tid];   // W_w is (64,33); col 32 hits zeros
    __syncthreads();
    const float* G = ws + OFF_G;
    float q = 0;
    for (int e = tid; e < 1024; e += 256) q += G[e]*sW[e>>5]*sW[e&31];
    q += __shfl_down(q, 32, 64);
    q += __shfl_down(q, 16, 64);
    q += __shfl_down(q,  8, 64);
    q += __shfl_down(q,  4, 64);
    q += __shfl_down(q,  2, 64);
    q += __shfl_down(q,  1, 64);
    if ((tid & 63) == 0) red[tid>>6] = q;
    if (tid < 32) sLin[tid] = sW[tid]*ws[OFF_SV + tid];
    __syncthreads();
    if (tid == 0) {
        float qs = red[0]+red[1]+red[2]+red[3];
        float lin = 0;
        for (int i = 0; i < 32; ++i) lin += sLin[i];
        const float Ninv = 1.0f/32768.0f;
        float wb = Wb[o];
        float mu  = lin*Ninv + wb;
        float E2  = qs*Ninv + 2.0f*wb*lin*Ninv + wb*wb;
        float var = E2 - mu*mu;
        float A = gamma[o] * rsqrtf(var + 1e-5f);
        float D = beta[o] - mu*A + A*wb;
        sAD[0] = A; sAD[1] = D;
        ws[OFF_D + o] = D;
    }
    __syncthreads();
    if (tid < 32) ws[OFF_AW + (o<<5) + tid] = sAD[0]*sW[tid];
}

// Final: reconstruct y tile, out[b,o,n] = Aw[o,:].y[b,n,:] + D[o] + x[b,o,n].
__global__ __launch_bounds__(256) void kFinal(
    const float* __restrict__ x, const float* __restrict__ ws, float* __restrict__ out)
{
    __shared__ float sy[64*33];    // pad 33: (4*n4+r+i)%32 -> 2-way max (free)
    __shared__ float sAw[64*33];
    __shared__ float sa[64];
    __shared__ int   sk[64];
    __shared__ float sD[64];
    int tid = threadIdx.x;
    int b = blockIdx.x >> 6;
    int n0 = (blockIdx.x & 63) << 6;
    if (tid < 64) {
        sa[tid] = ws[OFF_A + (b<<12) + n0 + tid];
        sk[tid] = ((const int*)ws)[OFF_KK + (b<<12) + n0 + tid];
        sD[tid] = ws[OFF_D + tid];
    }
    for (int e = tid; e < 2048; e += 256) {
        int o = e >> 5, i = e & 31;
        sAw[o*33 + i] = ws[OFF_AW + e];
    }
    __syncthreads();
    const float* S1 = ws + OFF_S1 + b*1025*32;
    const float* S2 = ws + OFF_S2 + b*1025*32;
    for (int e = tid; e < 2048; e += 256) {
        int nl = e >> 5, i = e & 31;
        int base = (sk[nl]<<5) + i;
        sy[nl*33 + i] = (sa[nl]*S1[base] + S2[base]) * (1.0f/1024.0f);
    }
    __syncthreads();
    for (int qq = 0; qq < 4; ++qq) {
        int e4 = tid + (qq<<8);
        int o = e4 >> 4, n4 = e4 & 15;
        const float* yr = &sy[(n4<<2)*33];
        const float* ar = &sAw[o*33];
        float4 acc = make_float4(0.f,0.f,0.f,0.f);
        #pragma unroll
        for (int i = 0; i < 32; ++i) {
            float w = ar[i];
            acc.x += w*yr[i];
            acc.y += w*yr[33+i];
            acc.z += w*yr[66+i];
            acc.w += w*yr[99+i];
        }
        int idx = ((b<<6) + o)*4096 + n0 + (n4<<2);
        float4 xv = *(const float4*)(x + idx);
        float d = sD[o];
        float4 ov;
        ov.x = acc.x + d + xv.x;
        ov.y = acc.y + d + xv.y;
        ov.z = acc.z + d + xv.z;
        ov.w = acc.w + d + xv.w;
        *(float4*)(out + idx) = ov;
    }
}

extern "C" void kernel_launch(void* const* d_in, const int* in_sizes, int n_in,
                              void* d_out, int out_size, void* d_ws, size_t ws_size,
                              hipStream_t stream)
{
    const float* x       = (const float*)d_in[0];
    const float* theta_w = (const float*)d_in[1];
    const float* theta_b = (const float*)d_in[2];
    const float* phi_w   = (const float*)d_in[3];
    const float* phi_b   = (const float*)d_in[4];
    const float* psi_w   = (const float*)d_in[5];
    const float* psi_b   = (const float*)d_in[6];
    const float* cp_w    = (const float*)d_in[7];
    const float* Ww      = (const float*)d_in[8];
    const float* Wb      = (const float*)d_in[9];
    const float* gamma   = (const float*)d_in[10];
    const float* beta    = (const float*)d_in[11];
    float* ws  = (float*)d_ws;
    float* out = (float*)d_out;

    hipMemsetAsync(ws + OFF_G, 0, (1024 + 32)*sizeof(float), stream);
    kA<<<1152, 256, 0, stream>>>(x, theta_w, theta_b, phi_w, phi_b,
                                 psi_w, psi_b, cp_w, ws);
    kRank<<<256, 256, 0, stream>>>(ws);
    kPrefix<<<8, 1024, 0, stream>>>(ws);
    kGram<<<256, 256, 0, stream>>>(ws);
    kStats<<<64, 256, 0, stream>>>(Ww, Wb, gamma, beta, ws);
    kFinal<<<512, 256, 0, stream>>>(x, ws, out);
}

// Round 2
// 147.551 us; speedup vs baseline: 1.0919x; 1.0919x over previous
//
#include <hip/hip_runtime.h>

// B=8, C=64, H=W=64, CI=32, N=4096 pixels, M=1024 pooled.
// rank-structured rewrite: y[b,n,:] = (a_n*S1[k_n,:] + S2[k_n,:])/1024
#define OFF_A    0         // a[b][n]              : 32768 floats
#define OFF_PSI  32768     // psi_pool[b][m][i]    : 262144
#define OFF_BB   294912    // bb[b][m]             : 8192
#define OFF_SBB  303104    // sorted-desc bb[b][k] : 8192
#define OFF_PERM 311296    // perm[b][k] (int)     : 8192
#define OFF_S1   319488    // S1[b][k<=1024][i]    : 262400
#define OFF_S2   581888    // S2[b][k<=1024][i]    : 262400
#define OFF_KK   844288    // k[b][n] (int)        : 32768
#define OFF_G8   877056    // per-batch Gram+SV    : 8*1056 = 8448
#define OFF_T1   885504    // T1[b][k][o]          : 8*1025*64 = 524800
#define OFF_T2   1410304   // T2[b][k][o]          : 524800
#define OFF_AD   1935104   // A[64], D[64]         : 128
// total ~7.74 MB of d_ws

// Kernel A: blocks [0,1024): fused phi/psi 1x1-conv + 2x2 maxpool; stores
// psi_pool and bb = w2 . phi_pool. Blocks [1024,1152): theta path collapsed:
// a[b,n] = x[b,:,n].tw_eff + tb_eff. Block 1024 also zeros the Gram copies.
__global__ __launch_bounds__(256) void kA(
    const float* __restrict__ x, const float* __restrict__ theta_w,
    const float* __restrict__ theta_b, const float* __restrict__ phi_w,
    const float* __restrict__ phi_b, const float* __restrict__ psi_w,
    const float* __restrict__ psi_b, const float* __restrict__ cp_w,
    float* ws)
{
    __shared__ float sm[4160];   // 2 x (32 rows x 65 padded) weight tiles
    int tid = threadIdx.x;
    int bid = blockIdx.x;
    if (bid < 1024) {
        for (int e = tid; e < 2048; e += 256) {
            int i = e >> 6, c = e & 63;
            sm[i*65 + c]        = phi_w[e];
            sm[2080 + i*65 + c] = psi_w[e];
        }
        __syncthreads();
        int t = (bid << 8) + tid;
        int i = t & 31;
        int m = (t >> 5) & 1023;
        int b = t >> 15;
        int ph = m >> 5, pw = m & 31;
        const float* xb = x + b*262144 + ph*128 + pw*2;
        const float* rp = sm + i*65;
        const float* rs = sm + 2080 + i*65;
        float p0=0,p1=0,p2=0,p3=0,s0=0,s1=0,s2=0,s3=0;
        #pragma unroll 8
        for (int c = 0; c < 64; ++c) {
            float2 xa = *(const float2*)(xb + c*4096);
            float2 xc = *(const float2*)(xb + c*4096 + 64);
            float wp = rp[c], wv = rs[c];
            p0 += xa.x*wp; p1 += xa.y*wp; p2 += xc.x*wp; p3 += xc.y*wp;
            s0 += xa.x*wv; s1 += xa.y*wv; s2 += xc.x*wv; s3 += xc.y*wv;
        }
        float pv = fmaxf(fmaxf(p0,p1), fmaxf(p2,p3)) + phi_b[i];
        float sv = fmaxf(fmaxf(s0,s1), fmaxf(s2,s3)) + psi_b[i];
        ws[OFF_PSI + (b<<15) + (m<<5) + i] = sv;
        float v = pv * cp_w[32 + i];
        v += __shfl_xor(v, 16, 32);
        v += __shfl_xor(v,  8, 32);
        v += __shfl_xor(v,  4, 32);
        v += __shfl_xor(v,  2, 32);
        v += __shfl_xor(v,  1, 32);
        if (i == 0) ws[OFF_BB + (b<<10) + m] = v;
    } else {
        if (bid == 1024) {  // zero Gram/SV copies (replaces hipMemsetAsync)
            for (int e = tid; e < 8448; e += 256) ws[OFF_G8 + e] = 0.0f;
        }
        if (tid < 64) {
            float s = 0;
            for (int i = 0; i < 32; ++i) s += cp_w[i]*theta_w[i*64 + tid];
            sm[tid] = s;
        } else if (tid == 64) {
            float s = 0;
            for (int i = 0; i < 32; ++i) s += cp_w[i]*theta_b[i];
            sm[64] = s;
        }
        __syncthreads();
        int t = ((bid - 1024) << 8) + tid;
        int n = t & 4095, b = t >> 12;
        const float* xb = x + b*262144 + n;
        float acc = sm[64];
        #pragma unroll 8
        for (int c = 0; c < 64; ++c) acc += xb[c*4096]*sm[c];
        ws[OFF_A + t] = acc;
    }
}

// Rank by counting (descending, index tiebreak), then scatter sorted value
// and permutation directly to global.
__global__ __launch_bounds__(256) void kRank(float* ws)
{
    __shared__ float sb[1024];
    int tid = threadIdx.x;
    int b = blockIdx.x >> 5, chunk = blockIdx.x & 31;
    const float* bb = ws + OFF_BB + (b<<10);
    for (int e = tid; e < 1024; e += 256) sb[e] = bb[e];
    __syncthreads();
    int ml = tid >> 3, jl = tid & 7;
    int m = (chunk<<5) + ml;
    float v = sb[m];
    int cnt = 0;
    for (int s = 0; s < 128; ++s) {
        int j = jl + (s<<3);
        float u = sb[j];
        cnt += (u > v || (u == v && j < m)) ? 1 : 0;
    }
    cnt += __shfl_xor(cnt, 1, 8);
    cnt += __shfl_xor(cnt, 2, 8);
    cnt += __shfl_xor(cnt, 4, 8);
    if (jl == 0) {
        ws[OFF_SBB + (b<<10) + cnt] = v;
        ((int*)ws)[OFF_PERM + (b<<10) + cnt] = m;
    }
}

// Prefix sums S1 (psi, sorted order) and S2 (bb*psi). 1 block/batch.
__global__ __launch_bounds__(1024) void kPrefix(float* ws)
{
    __shared__ float ssort[1024];
    __shared__ int   sperm[1024];
    __shared__ float sc1[1024];
    __shared__ float sc2[1024];
    int tid = threadIdx.x;
    int b = blockIdx.x;
    ssort[tid] = ws[OFF_SBB + (b<<10) + tid];
    sperm[tid] = ((const int*)ws)[OFF_PERM + (b<<10) + tid];
    __syncthreads();
    int i = tid & 31, ch = tid >> 5;     // 32 chunks x 32 elements
    const float* psi = ws + OFF_PSI + (b<<15);
    int j0 = ch << 5;
    float s1 = 0, s2 = 0;
    for (int j = 0; j < 32; ++j) {
        int jj = j0 + j;
        float p = psi[(sperm[jj]<<5) + i];
        s1 += p; s2 += ssort[jj]*p;
    }
    sc1[(ch<<5)+i] = s1; sc2[(ch<<5)+i] = s2;
    __syncthreads();
    if (tid < 32) {
        float run = 0;
        for (int c = 0; c < 32; ++c) { float t = sc1[(c<<5)+tid]; sc1[(c<<5)+tid] = run; run += t; }
    } else if (tid < 64) {
        int i2 = tid - 32;
        float run = 0;
        for (int c = 0; c < 32; ++c) { float t = sc2[(c<<5)+i2]; sc2[(c<<5)+i2] = run; run += t; }
    }
    __syncthreads();
    float run1 = sc1[(ch<<5)+i], run2 = sc2[(ch<<5)+i];
    float* S1 = ws + OFF_S1 + b*32800;   // 1025*32
    float* S2 = ws + OFF_S2 + b*32800;
    if (tid < 32) { S1[tid] = 0.0f; S2[tid] = 0.0f; }
    for (int j = 0; j < 32; ++j) {
        int jj = j0 + j;
        float p = psi[(sperm[jj]<<5) + i];
        run1 += p; run2 += ssort[jj]*p;
        S1[((jj+1)<<5) + i] = run1;
        S2[((jj+1)<<5) + i] = run2;
    }
}

// Per-tile: binary-search k_n, reconstruct y tile in LDS, accumulate
// PER-BATCH Gram + svec copies (32-way contention instead of 256-way).
__global__ __launch_bounds__(256) void kGram(float* ws)
{
    __shared__ float ssbb[1024];
    __shared__ float sy[4096];    // 128 n x 32 i
    __shared__ float sa[128];
    __shared__ int   sk[128];
    int tid = threadIdx.x;
    int b = blockIdx.x >> 5;
    int n0 = (blockIdx.x & 31) << 7;
    const float* sbbg = ws + OFF_SBB + (b<<10);
    for (int e = tid; e < 1024; e += 256) ssbb[e] = sbbg[e];
    __syncthreads();
    if (tid < 128) {
        int n = n0 + tid;
        float av = ws[OFF_A + (b<<12) + n];
        float t = -av;
        int lo = 0, hi = 1024;
        while (lo < hi) { int mid = (lo+hi)>>1; if (ssbb[mid] > t) lo = mid+1; else hi = mid; }
        sa[tid] = av; sk[tid] = lo;
        ((int*)ws)[OFF_KK + (b<<12) + n] = lo;
    }
    __syncthreads();
    const float* S1 = ws + OFF_S1 + b*32800;
    const float* S2 = ws + OFF_S2 + b*32800;
    for (int e = tid; e < 4096; e += 256) {
        int nl = e >> 5, i = e & 31;
        int base = (sk[nl]<<5) + i;
        sy[e] = (sa[nl]*S1[base] + S2[base]) * (1.0f/1024.0f);
    }
    __syncthreads();
    int i = tid >> 3, j0 = (tid & 7) << 2;
    float4 acc = make_float4(0.f,0.f,0.f,0.f);
    for (int s = 0; s < 128; ++s) {
        float  yi = sy[(s<<5) + i];
        float4 yj = *(const float4*)&sy[(s<<5) + j0];
        acc.x += yi*yj.x; acc.y += yi*yj.y; acc.z += yi*yj.z; acc.w += yi*yj.w;
    }
    float* G = ws + OFF_G8 + b*1056;
    atomicAdd(&G[(i<<5)+j0+0], acc.x);
    atomicAdd(&G[(i<<5)+j0+1], acc.y);
    atomicAdd(&G[(i<<5)+j0+2], acc.z);
    atomicAdd(&G[(i<<5)+j0+3], acc.w);
    if (tid < 32) {
        float sv = 0;
        for (int s = 0; s < 128; ++s) sv += sy[(s<<5) + tid];
        atomicAdd(&G[1024 + tid], sv);
    }
}

// T1[b][k][o] = (1/1024) * sum_i Ww[o][i]*S1[b][k][i]; same for T2.
// Grid: 8 batches x 17 k-tiles of 64. Runs before kStats (independent of Gram).
__global__ __launch_bounds__(256) void kT(
    const float* __restrict__ Ww, float* ws)
{
    __shared__ float sS1[2048];   // 64 k-rows x 32 i
    __shared__ float sS2[2048];
    int tid = threadIdx.x;
    int bid = blockIdx.x;
    int b = bid / 17, kt = bid % 17;
    int k0 = kt << 6;
    const float* S1 = ws + OFF_S1 + b*32800;
    const float* S2 = ws + OFF_S2 + b*32800;
    for (int e = tid; e < 2048; e += 256) {
        int k = k0 + (e >> 5);
        sS1[e] = (k <= 1024) ? S1[(k<<5) + (e&31)] : 0.0f;
        sS2[e] = (k <= 1024) ? S2[(k<<5) + (e&31)] : 0.0f;
    }
    __syncthreads();
    int o = tid & 63, kg = tid >> 6;     // 4 groups x 16 k each
    float w[32];
    #pragma unroll
    for (int i = 0; i < 32; ++i) w[i] = Ww[o*33 + i];
    float* T1 = ws + OFF_T1 + b*65600;   // 1025*64
    float* T2 = ws + OFF_T2 + b*65600;
    for (int kk = 0; kk < 16; ++kk) {
        int kl = (kg << 4) + kk;
        int k = k0 + kl;
        if (k > 1024) break;
        const float* r1 = &sS1[kl << 5];
        const float* r2 = &sS2[kl << 5];
        float t1 = 0, t2 = 0;
        #pragma unroll
        for (int q = 0; q < 8; ++q) {
            float4 a1 = *(const float4*)&r1[q<<2];
            float4 a2 = *(const float4*)&r2[q<<2];
            t1 += a1.x*w[(q<<2)] + a1.y*w[(q<<2)+1] + a1.z*w[(q<<2)+2] + a1.w*w[(q<<2)+3];
            t2 += a2.x*w[(q<<2)] + a2.y*w[(q<<2)+1] + a2.z*w[(q<<2)+2] + a2.w*w[(q<<2)+3];
        }
        T1[(k<<6) + o] = t1 * (1.0f/1024.0f);
        T2[(k<<6) + o] = t2 * (1.0f/1024.0f);
    }
}

// Closed-form BN from summed Gram copies; emits A[o], D[o].
__global__ __launch_bounds__(256) void kStats(
    const float* __restrict__ Ww, const float* __restrict__ Wb,
    const float* __restrict__ gamma, const float* __restrict__ beta,
    float* ws)
{
    __shared__ float sW[32];
    __shared__ float red[4];
    __shared__ float sLin[32];
    int tid = threadIdx.x;
    int o = blockIdx.x;
    if (tid < 32) sW[tid] = Ww[o*33 + tid];
    __syncthreads();
    const float* G8 = ws + OFF_G8;
    float q = 0;
    for (int e = tid; e < 1024; e += 256) {
        float g = 0;
        #pragma unroll
        for (int c = 0; c < 8; ++c) g += G8[c*1056 + e];
        q += g*sW[e>>5]*sW[e&31];
    }
    q += __shfl_down(q, 32, 64);
    q += __shfl_down(q, 16, 64);
    q += __shfl_down(q,  8, 64);
    q += __shfl_down(q,  4, 64);
    q += __shfl_down(q,  2, 64);
    q += __shfl_down(q,  1, 64);
    if ((tid & 63) == 0) red[tid>>6] = q;
    if (tid < 32) {
        float sv = 0;
        #pragma unroll
        for (int c = 0; c < 8; ++c) sv += G8[c*1056 + 1024 + tid];
        sLin[tid] = sW[tid]*sv;
    }
    __syncthreads();
    if (tid == 0) {
        float qs = red[0]+red[1]+red[2]+red[3];
        float lin = 0;
        for (int i = 0; i < 32; ++i) lin += sLin[i];
        const float Ninv = 1.0f/32768.0f;
        float wb = Wb[o];
        float mu  = lin*Ninv + wb;
        float E2  = qs*Ninv + 2.0f*wb*lin*Ninv + wb*wb;
        float var = E2 - mu*mu;
        float A = gamma[o] * rsqrtf(var + 1e-5f);
        float D = beta[o] - mu*A + A*wb;
        ws[OFF_AD + o]      = A;
        ws[OFF_AD + 64 + o] = D;
    }
}

// Final: out[b,o,n] = A[o]*(a_n*T1[k_n,o] + T2[k_n,o]) + D[o] + x[b,o,n].
// Gather T rows coalesced (lanes over o), transpose through LDS, store
// coalesced (lanes over n).
__global__ __launch_bounds__(256) void kFinal(
    const float* __restrict__ x, const float* __restrict__ ws, float* __restrict__ out)
{
    __shared__ float tile[64*65];   // [o][n], pad 65
    __shared__ float sa[64];
    __shared__ int   sk[64];
    __shared__ float sA[64];
    __shared__ float sD[64];
    int tid = threadIdx.x;
    int b = blockIdx.x >> 6;
    int n0 = (blockIdx.x & 63) << 6;
    if (tid < 64) {
        sa[tid] = ws[OFF_A + (b<<12) + n0 + tid];
        sk[tid] = ((const int*)ws)[OFF_KK + (b<<12) + n0 + tid];
        sA[tid] = ws[OFF_AD + tid];
        sD[tid] = ws[OFF_AD + 64 + tid];
    }
    __syncthreads();
    const float* T1 = ws + OFF_T1 + b*65600;
    const float* T2 = ws + OFF_T2 + b*65600;
    {
        int o = tid & 63, ng = tid >> 6;
        float Ao = sA[o], Do = sD[o];
        for (int j = 0; j < 16; ++j) {
            int n = (ng << 4) + j;
            int k = sk[n];
            float a = sa[n];
            float t1 = T1[(k<<6) + o];
            float t2 = T2[(k<<6) + o];
            tile[o*65 + n] = Ao*(a*t1 + t2) + Do;
        }
    }
    __syncthreads();
    {
        int n = tid & 63, og = tid >> 6;
        for (int j = 0; j < 16; ++j) {
            int o = (og << 4) + j;
            int idx = ((b<<6) + o)*4096 + n0 + n;
            out[idx] = tile[o*65 + n] + x[idx];
        }
    }
}

extern "C" void kernel_launch(void* const* d_in, const int* in_sizes, int n_in,
                              void* d_out, int out_size, void* d_ws, size_t ws_size,
                              hipStream_t stream)
{
    const float* x       = (const float*)d_in[0];
    const float* theta_w = (const float*)d_in[1];
    const float* theta_b = (const float*)d_in[2];
    const float* phi_w   = (const float*)d_in[3];
    const float* phi_b   = (const float*)d_in[4];
    const float* psi_w   = (const float*)d_in[5];
    const float* psi_b   = (const float*)d_in[6];
    const float* cp_w    = (const float*)d_in[7];
    const float* Ww      = (const float*)d_in[8];
    const float* Wb      = (const float*)d_in[9];
    const float* gamma   = (const float*)d_in[10];
    const float* beta    = (const float*)d_in[11];
    float* ws  = (float*)d_ws;
    float* out = (float*)d_out;

    kA<<<1152, 256, 0, stream>>>(x, theta_w, theta_b, phi_w, phi_b,
                                 psi_w, psi_b, cp_w, ws);
    kRank<<<256, 256, 0, stream>>>(ws);
    kPrefix<<<8, 1024, 0, stream>>>(ws);
    kGram<<<256, 256, 0, stream>>>(ws);
    kT<<<136, 256, 0, stream>>>(Ww, ws);
    kStats<<<64, 256, 0, stream>>>(Ww, Wb, gamma, beta, ws);
    kFinal<<<512, 256, 0, stream>>>(x, ws, out);
}

// Round 3
// 142.997 us; speedup vs baseline: 1.1267x; 1.0318x over previous
//
#include <hip/hip_runtime.h>

// B=8, C=64, H=W=64, CI=32, N=4096 pixels, M=1024 pooled.
// y[b,n,:] = (a_n*S1[k_n,:] + S2[k_n,:])/1024 ; only W_w . y is ever needed,
// so we track U = Ww.psi (64-dim) and its sorted prefixes T1/T2 directly.
// BN stats come from per-k scalars (cnt, sum a, sum a^2) x T rows - no Gram.
#define OFF_A    0         // a[b][n]               : 32768 floats
#define OFF_BB   32768     // bb[b][m]              : 8192
#define OFF_SBB  40960     // sorted-desc bb[b][k]  : 8192
#define OFF_PERM 49152     // perm[b][k] (int)      : 8192
#define OFF_U    57344     // U[b][m][o]            : 8*1024*64 = 524288
#define OFF_T1   581632    // T1[b][k<=1024][o]     : 8*1025*64 = 524800
#define OFF_T2   1106432   // T2[b][k][o]           : 524800
#define OFF_KK   1631232   // k[b][n] (int)         : 32768
#define OFF_M    1664000   // M1[64] (sum wy_inner), M2[64] (sum wy_inner^2)
// total ~6.7 MB of d_ws

// Kernel A: blocks [0,1024): fused phi/psi 1x1-conv + 2x2 maxpool;
// bb = w2 . phi_pool (shuffle-reduced); U[m][o] = Ww[o,:] . psi_pool[m,:]
// via LDS transpose (psi never hits global). Blocks [1024,1152): theta path
// collapsed: a[b,n] = x[b,:,n].tw_eff + tb_eff. Block 1024 zeros M1/M2.
__global__ __launch_bounds__(256) void kA(
    const float* __restrict__ x, const float* __restrict__ theta_w,
    const float* __restrict__ theta_b, const float* __restrict__ phi_w,
    const float* __restrict__ phi_b, const float* __restrict__ psi_w,
    const float* __restrict__ psi_b, const float* __restrict__ cp_w,
    const float* __restrict__ Ww, float* ws)
{
    __shared__ float sm[4160];    // 2 x (32 rows x 65 padded) conv weights
    __shared__ float spsi[8*33];  // 8 m-rows x 32 i (padded)
    __shared__ float sWw[64*33];  // 64 o-rows x 32 i (padded)
    int tid = threadIdx.x;
    int bid = blockIdx.x;
    if (bid < 1024) {
        for (int e = tid; e < 2048; e += 256) {
            int i = e >> 6, c = e & 63;
            sm[i*65 + c]        = phi_w[e];
            sm[2080 + i*65 + c] = psi_w[e];
        }
        for (int e = tid; e < 2048; e += 256)
            sWw[(e >> 5)*33 + (e & 31)] = Ww[(e >> 5)*33 + (e & 31)];
        __syncthreads();
        int t = (bid << 8) + tid;
        int i = t & 31;
        int m = (t >> 5) & 1023;
        int b = t >> 15;
        int ph = m >> 5, pw = m & 31;
        const float* xb = x + b*262144 + ph*128 + pw*2;
        const float* rp = sm + i*65;          // bank (i+c)%32: conflict-free
        const float* rs = sm + 2080 + i*65;
        float p0=0,p1=0,p2=0,p3=0,s0=0,s1=0,s2=0,s3=0;
        #pragma unroll 8
        for (int c = 0; c < 64; ++c) {
            float2 xa = *(const float2*)(xb + c*4096);
            float2 xc = *(const float2*)(xb + c*4096 + 64);
            float wp = rp[c], wv = rs[c];
            p0 += xa.x*wp; p1 += xa.y*wp; p2 += xc.x*wp; p3 += xc.y*wp;
            s0 += xa.x*wv; s1 += xa.y*wv; s2 += xc.x*wv; s3 += xc.y*wv;
        }
        float pv = fmaxf(fmaxf(p0,p1), fmaxf(p2,p3)) + phi_b[i];
        float sv = fmaxf(fmaxf(s0,s1), fmaxf(s2,s3)) + psi_b[i];
        spsi[(tid >> 5)*33 + i] = sv;
        float v = pv * cp_w[32 + i];
        v += __shfl_xor(v, 16, 32);
        v += __shfl_xor(v,  8, 32);
        v += __shfl_xor(v,  4, 32);
        v += __shfl_xor(v,  2, 32);
        v += __shfl_xor(v,  1, 32);
        if (i == 0) ws[OFF_BB + (b<<10) + m] = v;
        __syncthreads();
        int m0 = (bid & 127) << 3;
        #pragma unroll
        for (int rep = 0; rep < 2; ++rep) {
            int idx = tid + (rep << 8);       // 512 outputs = 8 m x 64 o
            int ml = idx >> 6, o = idx & 63;
            const float* pr = &spsi[ml*33];   // wave-uniform ml: broadcast
            const float* wr = &sWw[o*33];     // (o+i)%32: 2-way max (free)
            float u = 0;
            #pragma unroll
            for (int i2 = 0; i2 < 32; ++i2) u += pr[i2]*wr[i2];
            ws[OFF_U + (((b<<10) + m0 + ml) << 6) + o] = u;
        }
    } else {
        if (bid == 1024 && tid < 128) ws[OFF_M + tid] = 0.0f;
        if (tid < 64) {
            float s = 0;
            for (int i = 0; i < 32; ++i) s += cp_w[i]*theta_w[i*64 + tid];
            sm[tid] = s;
        } else if (tid == 64) {
            float s = 0;
            for (int i = 0; i < 32; ++i) s += cp_w[i]*theta_b[i];
            sm[64] = s;
        }
        __syncthreads();
        int t = ((bid - 1024) << 8) + tid;
        int n = t & 4095, b = t >> 12;
        const float* xb = x + b*262144 + n;
        float acc = sm[64];
        #pragma unroll 8
        for (int c = 0; c < 64; ++c) acc += xb[c*4096]*sm[c];
        ws[OFF_A + t] = acc;
    }
}

// Rank by counting (descending, index tiebreak), scatter sorted value + perm.
__global__ __launch_bounds__(256) void kRank(float* ws)
{
    __shared__ float sb[1024];
    int tid = threadIdx.x;
    int b = blockIdx.x >> 5, chunk = blockIdx.x & 31;
    const float* bb = ws + OFF_BB + (b<<10);
    for (int e = tid; e < 1024; e += 256) sb[e] = bb[e];
    __syncthreads();
    int ml = tid >> 3, jl = tid & 7;
    int m = (chunk<<5) + ml;
    float v = sb[m];
    int cnt = 0;
    for (int s = 0; s < 128; ++s) {
        int j = jl + (s<<3);
        float u = sb[j];
        cnt += (u > v || (u == v && j < m)) ? 1 : 0;
    }
    cnt += __shfl_xor(cnt, 1, 8);
    cnt += __shfl_xor(cnt, 2, 8);
    cnt += __shfl_xor(cnt, 4, 8);
    if (jl == 0) {
        ws[OFF_SBB + (b<<10) + cnt] = v;
        ((int*)ws)[OFF_PERM + (b<<10) + cnt] = m;
    }
}

// kPS: per (batch, o-half) block: binary-search k_n + histogram (cnt, sum a,
// sum a^2) in LDS; chunked prefix of U in sorted order -> T1/T2; BN moment
// partials M1/M2 accumulated on the fly.
__global__ __launch_bounds__(1024) void kPS(float* ws)
{
    __shared__ float ssort[1024];
    __shared__ int   sperm[1024];
    __shared__ float sc1[1024];
    __shared__ float sc2[1024];
    __shared__ float hcnt[1025], hsa[1025], hsa2[1025];
    int tid = threadIdx.x;
    int b = blockIdx.x >> 1, oh = blockIdx.x & 1;
    int obase = oh << 5;
    ssort[tid] = ws[OFF_SBB + (b<<10) + tid];
    sperm[tid] = ((const int*)ws)[OFF_PERM + (b<<10) + tid];
    for (int e = tid; e < 1025; e += 1024) { hcnt[e]=0; hsa[e]=0; hsa2[e]=0; }
    __syncthreads();
    const float* ag = ws + OFF_A + (b<<12);
    int* kk = (int*)ws + OFF_KK + (b<<12);
    for (int q = 0; q < 4; ++q) {
        int n = (q<<10) + tid;
        float av = ag[n];
        float tt = -av;
        int lo = 0, hi = 1024;
        #pragma unroll
        for (int s = 0; s < 10; ++s) {
            int mid = (lo+hi)>>1;
            if (ssort[mid] > tt) lo = mid+1; else hi = mid;
        }
        if (oh == 0) kk[n] = lo;
        atomicAdd(&hcnt[lo], 1.0f);
        atomicAdd(&hsa[lo], av);
        atomicAdd(&hsa2[lo], av*av);
    }
    __syncthreads();
    int o = tid & 31, ch = tid >> 5;     // 32 chunks x 32 sorted rows
    const float* Ub = ws + OFF_U + (b<<16);
    float s1 = 0, s2 = 0;
    for (int jl = 0; jl < 32; ++jl) {
        int jj = (ch<<5) + jl;
        float p = Ub[(sperm[jj]<<6) + obase + o];
        s1 += p; s2 += ssort[jj]*p;
    }
    sc1[(ch<<5)+o] = s1; sc2[(ch<<5)+o] = s2;
    __syncthreads();
    if (tid < 32) {
        float run = 0;
        for (int c = 0; c < 32; ++c) { float t = sc1[(c<<5)+tid]; sc1[(c<<5)+tid] = run; run += t; }
    } else if (tid < 64) {
        int o2 = tid - 32;
        float run = 0;
        for (int c = 0; c < 32; ++c) { float t = sc2[(c<<5)+o2]; sc2[(c<<5)+o2] = run; run += t; }
    }
    __syncthreads();
    float run1 = sc1[(ch<<5)+o], run2 = sc2[(ch<<5)+o];
    float* T1 = ws + OFF_T1 + b*65600;   // 1025*64
    float* T2 = ws + OFF_T2 + b*65600;
    if (tid < 32) { T1[obase + tid] = 0.0f; T2[obase + tid] = 0.0f; }  // k=0 row
    const float inv = 1.0f/1024.0f;
    float m1 = 0, m2 = 0;
    for (int jl = 0; jl < 32; ++jl) {
        int jj = (ch<<5) + jl;
        float p = Ub[(sperm[jj]<<6) + obase + o];
        run1 += p; run2 += ssort[jj]*p;
        float t1 = run1*inv, t2 = run2*inv;
        int k = jj + 1;
        T1[(k<<6) + obase + o] = t1;
        T2[(k<<6) + obase + o] = t2;
        float c = hcnt[k], sa = hsa[k], sa2 = hsa2[k];   // wave-uniform k
        m1 += sa*t1 + c*t2;
        m2 += sa2*t1*t1 + 2.0f*sa*t1*t2 + c*t2*t2;
    }
    __syncthreads();
    sc1[(ch<<5)+o] = m1; sc2[(ch<<5)+o] = m2;
    __syncthreads();
    if (tid < 32) {
        float s = 0;
        for (int c = 0; c < 32; ++c) s += sc1[(c<<5)+tid];
        atomicAdd(&ws[OFF_M + obase + tid], s);
    } else if (tid < 64) {
        int o2 = tid - 32;
        float s = 0;
        for (int c = 0; c < 32; ++c) s += sc2[(c<<5)+o2];
        atomicAdd(&ws[OFF_M + 64 + obase + o2], s);
    }
}

// Final: A/D from moments inline; out[b,o,n]=A[o]*(a_n*T1[k_n,o]+T2[k_n,o])
// + D[o] + x[b,o,n]. Gather coalesced over o, transpose in LDS, store over n.
__global__ __launch_bounds__(256) void kFinal(
    const float* __restrict__ x, const float* __restrict__ Wb,
    const float* __restrict__ gamma, const float* __restrict__ beta,
    const float* __restrict__ ws, float* __restrict__ out)
{
    __shared__ float tile[64*65];
    __shared__ float sa[64];
    __shared__ int   sk[64];
    __shared__ float sA[64];
    __shared__ float sD[64];
    int tid = threadIdx.x;
    int b = blockIdx.x >> 6;
    int n0 = (blockIdx.x & 63) << 6;
    if (tid < 64) {
        sa[tid] = ws[OFF_A + (b<<12) + n0 + tid];
        sk[tid] = ((const int*)ws)[OFF_KK + (b<<12) + n0 + tid];
        const float Ninv = 1.0f/32768.0f;
        float m1 = ws[OFF_M + tid] * Ninv;
        float m2 = ws[OFF_M + 64 + tid] * Ninv;
        float wb = Wb[tid];
        float mu  = m1 + wb;
        float E2  = m2 + 2.0f*wb*m1 + wb*wb;
        float var = E2 - mu*mu;
        float A = gamma[tid] * rsqrtf(var + 1e-5f);
        sA[tid] = A;
        sD[tid] = beta[tid] + A*(wb - mu);
    }
    __syncthreads();
    const float* T1 = ws + OFF_T1 + b*65600;
    const float* T2 = ws + OFF_T2 + b*65600;
    {
        int o = tid & 63, ng = tid >> 6;
        float Ao = sA[o], Do = sD[o];
        for (int j = 0; j < 16; ++j) {
            int n = (ng << 4) + j;
            int k = sk[n];
            float a = sa[n];
            float t1 = T1[(k<<6) + o];
            float t2 = T2[(k<<6) + o];
            tile[o*65 + n] = Ao*(a*t1 + t2) + Do;
        }
    }
    __syncthreads();
    {
        int n = tid & 63, og = tid >> 6;
        for (int j = 0; j < 16; ++j) {
            int o = (og << 4) + j;
            int idx = ((b<<6) + o)*4096 + n0 + n;
            out[idx] = tile[o*65 + n] + x[idx];
        }
    }
}

extern "C" void kernel_launch(void* const* d_in, const int* in_sizes, int n_in,
                              void* d_out, int out_size, void* d_ws, size_t ws_size,
                              hipStream_t stream)
{
    const float* x       = (const float*)d_in[0];
    const float* theta_w = (const float*)d_in[1];
    const float* theta_b = (const float*)d_in[2];
    const float* phi_w   = (const float*)d_in[3];
    const float* phi_b   = (const float*)d_in[4];
    const float* psi_w   = (const float*)d_in[5];
    const float* psi_b   = (const float*)d_in[6];
    const float* cp_w    = (const float*)d_in[7];
    const float* Ww      = (const float*)d_in[8];
    const float* Wb      = (const float*)d_in[9];
    const float* gamma   = (const float*)d_in[10];
    const float* beta    = (const float*)d_in[11];
    float* ws  = (float*)d_ws;
    float* out = (float*)d_out;

    kA<<<1152, 256, 0, stream>>>(x, theta_w, theta_b, phi_w, phi_b,
                                 psi_w, psi_b, cp_w, Ww, ws);
    kRank<<<256, 256, 0, stream>>>(ws);
    kPS<<<16, 1024, 0, stream>>>(ws);
    kFinal<<<512, 256, 0, stream>>>(x, Wb, gamma, beta, ws, out);
}

// Round 4
// 132.908 us; speedup vs baseline: 1.2122x; 1.0759x over previous
//
#include <hip/hip_runtime.h>

// B=8, C=64, H=W=64, CI=32, N=4096 pixels, M=1024 pooled.
// y[b,n,:] = (a_n*S1[k_n,:] + S2[k_n,:])/1024 ; only W_w . y is needed, so
// track U = Ww.psi (64-dim) and its sorted-order prefixes T1/T2 directly.
// BN stats from per-k scalars (cnt, sum a, sum a^2) x T rows - no Gram.
#define OFF_A    0         // a[b][n]               : 32768 floats
#define OFF_BB   32768     // bb[b][m]              : 8192
#define OFF_SBB  40960     // sorted-desc bb[b][k]  : 8192
#define OFF_PERM 49152     // perm[b][k] (int)      : 8192
#define OFF_U    57344     // U[b][m][o]            : 8*1024*64 = 524288
#define OFF_T1   581632    // T1[b][k<=1024][o]     : 8*1025*64 = 524800
#define OFF_T2   1106432   // T2[b][k][o]           : 524800
#define OFF_KK   1631232   // k[b][n] (int)         : 32768
#define OFF_M    1664000   // M1[64], M2[64]        : 128
#define OFF_HC   1664128   // hist cnt[b][1025]     : 8200
#define OFF_HS   1672328   // hist sum_a[b][1025]   : 8200
#define OFF_HS2  1680528   // hist sum_a2[b][1025]  : 8200
// total 1688728 floats ~ 6.76 MB of d_ws

// Kernel A: blocks [0,1024): fused phi/psi 1x1-conv + 2x2 maxpool;
// bb = w2 . phi_pool (shuffle-reduced); U[m][o] = Ww[o,:] . psi_pool[m,:]
// via LDS transpose. Blocks [1024,1152): theta path collapsed:
// a[b,n] = x[b,:,n].tw_eff + tb_eff. Block 1024 zeros M + hist.
__global__ __launch_bounds__(256) void kA(
    const float* __restrict__ x, const float* __restrict__ theta_w,
    const float* __restrict__ theta_b, const float* __restrict__ phi_w,
    const float* __restrict__ phi_b, const float* __restrict__ psi_w,
    const float* __restrict__ psi_b, const float* __restrict__ cp_w,
    const float* __restrict__ Ww, float* ws)
{
    __shared__ float sm[4160];    // 2 x (32 rows x 65 padded) conv weights
    __shared__ float spsi[8*33];  // 8 m-rows x 32 i (padded)
    __shared__ float sWw[64*33];  // 64 o-rows x 32 i (padded)
    int tid = threadIdx.x;
    int bid = blockIdx.x;
    if (bid < 1024) {
        for (int e = tid; e < 2048; e += 256) {
            int i = e >> 6, c = e & 63;
            sm[i*65 + c]        = phi_w[e];
            sm[2080 + i*65 + c] = psi_w[e];
        }
        for (int e = tid; e < 2048; e += 256)
            sWw[(e >> 5)*33 + (e & 31)] = Ww[(e >> 5)*33 + (e & 31)];
        __syncthreads();
        int t = (bid << 8) + tid;
        int i = t & 31;
        int m = (t >> 5) & 1023;
        int b = t >> 15;
        int ph = m >> 5, pw = m & 31;
        const float* xb = x + b*262144 + ph*128 + pw*2;
        const float* rp = sm + i*65;          // bank (i+c)%32: conflict-free
        const float* rs = sm + 2080 + i*65;
        float p0=0,p1=0,p2=0,p3=0,s0=0,s1=0,s2=0,s3=0;
        #pragma unroll 8
        for (int c = 0; c < 64; ++c) {
            float2 xa = *(const float2*)(xb + c*4096);
            float2 xc = *(const float2*)(xb + c*4096 + 64);
            float wp = rp[c], wv = rs[c];
            p0 += xa.x*wp; p1 += xa.y*wp; p2 += xc.x*wp; p3 += xc.y*wp;
            s0 += xa.x*wv; s1 += xa.y*wv; s2 += xc.x*wv; s3 += xc.y*wv;
        }
        float pv = fmaxf(fmaxf(p0,p1), fmaxf(p2,p3)) + phi_b[i];
        float sv = fmaxf(fmaxf(s0,s1), fmaxf(s2,s3)) + psi_b[i];
        spsi[(tid >> 5)*33 + i] = sv;
        float v = pv * cp_w[32 + i];
        v += __shfl_xor(v, 16, 32);
        v += __shfl_xor(v,  8, 32);
        v += __shfl_xor(v,  4, 32);
        v += __shfl_xor(v,  2, 32);
        v += __shfl_xor(v,  1, 32);
        if (i == 0) ws[OFF_BB + (b<<10) + m] = v;
        __syncthreads();
        int m0 = (bid & 127) << 3;
        #pragma unroll
        for (int rep = 0; rep < 2; ++rep) {
            int idx = tid + (rep << 8);       // 512 outputs = 8 m x 64 o
            int ml = idx >> 6, o = idx & 63;
            const float* pr = &spsi[ml*33];   // wave-uniform ml: broadcast
            const float* wr = &sWw[o*33];     // (o+i)%32: 2-way max (free)
            float u = 0;
            #pragma unroll
            for (int i2 = 0; i2 < 32; ++i2) u += pr[i2]*wr[i2];
            ws[OFF_U + (((b<<10) + m0 + ml) << 6) + o] = u;
        }
    } else {
        if (bid == 1024) {   // zero M + hist (contiguous 128+24600 floats)
            for (int e = tid; e < 24728; e += 256) ws[OFF_M + e] = 0.0f;
        }
        if (tid < 64) {
            float s = 0;
            for (int i = 0; i < 32; ++i) s += cp_w[i]*theta_w[i*64 + tid];
            sm[tid] = s;
        } else if (tid == 64) {
            float s = 0;
            for (int i = 0; i < 32; ++i) s += cp_w[i]*theta_b[i];
            sm[64] = s;
        }
        __syncthreads();
        int t = ((bid - 1024) << 8) + tid;
        int n = t & 4095, b = t >> 12;
        const float* xb = x + b*262144 + n;
        float acc = sm[64];
        #pragma unroll 8
        for (int c = 0; c < 64; ++c) acc += xb[c*4096]*sm[c];
        ws[OFF_A + t] = acc;
    }
}

// kRank: (b, chunk) blocks. Part 1: rank 32 m's by counting (descending,
// index tiebreak), scatter sorted value + perm. Part 2: k_n for 128 pixels
// by direct count (k_n = #{m: bb_m > -a_n}) + histogram atomics.
__global__ __launch_bounds__(256) void kRank(float* ws)
{
    __shared__ float sb[1024];
    int tid = threadIdx.x;
    int b = blockIdx.x >> 5, chunk = blockIdx.x & 31;
    const float* bb = ws + OFF_BB + (b<<10);
    for (int e = tid; e < 1024; e += 256) sb[e] = bb[e];
    __syncthreads();
    {   // part 1: rank
        int ml = tid >> 3, jl = tid & 7;
        int m = (chunk<<5) + ml;
        float v = sb[m];
        int cnt = 0;
        for (int s = 0; s < 128; ++s) {
            int j = jl + (s<<3);
            float u = sb[j];
            cnt += (u > v || (u == v && j < m)) ? 1 : 0;
        }
        cnt += __shfl_xor(cnt, 1, 8);
        cnt += __shfl_xor(cnt, 2, 8);
        cnt += __shfl_xor(cnt, 4, 8);
        if (jl == 0) {
            ws[OFF_SBB + (b<<10) + cnt] = v;
            ((int*)ws)[OFF_PERM + (b<<10) + cnt] = m;
        }
    }
    {   // part 2: k_n + hist (2 threads per pixel, float2 LDS reads)
        int l = tid >> 1, jl = tid & 1;
        int n = (chunk<<7) + l;
        float av = ws[OFF_A + (b<<12) + n];
        float tt = -av;
        const float2* sb2 = (const float2*)sb;
        int cnt = 0;
        for (int s = 0; s < 256; ++s) {
            float2 u = sb2[jl + (s<<1)];   // 2 distinct addrs/wave: free
            cnt += (u.x > tt) ? 1 : 0;
            cnt += (u.y > tt) ? 1 : 0;
        }
        cnt += __shfl_xor(cnt, 1, 64);
        if (jl == 0) {
            ((int*)ws)[OFF_KK + (b<<12) + n] = cnt;
            atomicAdd(&ws[OFF_HC + b*1025 + cnt], 1.0f);
            atomicAdd(&ws[OFF_HS + b*1025 + cnt], av);
            atomicAdd(&ws[OFF_HS2 + b*1025 + cnt], av*av);
        }
    }
}

// kPS: (b, o-group of 8) blocks, 1024 threads = 128 chunks x 8 o.
// Register-cached gathers of U in sorted order, shuffle two-level scan ->
// T1/T2 prefixes; BN moment partials from hist x T accumulated inline.
__global__ __launch_bounds__(1024) void kPS(float* ws)
{
    __shared__ float ssort[1024];
    __shared__ int   sperm[1024];
    __shared__ float shc[1025], shs[1025], shs2[1025];
    __shared__ float swp1[128], swp2[128];   // per-(wave,o) partials
    int tid = threadIdx.x;
    int b = blockIdx.x >> 3, og = blockIdx.x & 7;
    int obase = og << 3;
    ssort[tid] = ws[OFF_SBB + (b<<10) + tid];
    sperm[tid] = ((const int*)ws)[OFF_PERM + (b<<10) + tid];
    shc[tid]  = ws[OFF_HC  + b*1025 + tid];
    shs[tid]  = ws[OFF_HS  + b*1025 + tid];
    shs2[tid] = ws[OFF_HS2 + b*1025 + tid];
    if (tid == 0) {
        shc[1024]  = ws[OFF_HC  + b*1025 + 1024];
        shs[1024]  = ws[OFF_HS  + b*1025 + 1024];
        shs2[1024] = ws[OFF_HS2 + b*1025 + 1024];
    }
    __syncthreads();
    int ch = tid >> 3, o = tid & 7;
    int wv = tid >> 6, chl = (tid & 63) >> 3;   // ch = wv*8 + chl
    const float* Ub = ws + OFF_U + (b<<16) + obase + o;
    float p[8], sp[8];
    float s1 = 0, s2 = 0;
    #pragma unroll
    for (int jl = 0; jl < 8; ++jl) {
        int jj = (ch<<3) + jl;
        float v = Ub[sperm[jj]<<6];
        p[jl] = v;
        sp[jl] = ssort[jj]*v;
        s1 += v; s2 += sp[jl];
    }
    float own1 = s1, own2 = s2;
    // intra-wave inclusive scan over chl (8 chunks/wave)
    #pragma unroll
    for (int d = 1; d < 8; d <<= 1) {
        float u1 = __shfl_up(s1, d<<3, 64);
        float u2 = __shfl_up(s2, d<<3, 64);
        if (chl >= d) { s1 += u1; s2 += u2; }
    }
    if (chl == 7) { swp1[(wv<<3)+o] = s1; swp2[(wv<<3)+o] = s2; }
    __syncthreads();
    float off1 = 0, off2 = 0;
    for (int w = 0; w < 16; ++w) {
        if (w < wv) { off1 += swp1[(w<<3)+o]; off2 += swp2[(w<<3)+o]; }
    }
    float run1 = off1 + s1 - own1;   // exclusive prefix before chunk ch
    float run2 = off2 + s2 - own2;
    float* T1 = ws + OFF_T1 + b*65600 + obase + o;
    float* T2 = ws + OFF_T2 + b*65600 + obase + o;
    if (ch == 0) { T1[0] = 0.0f; T2[0] = 0.0f; }   // k=0 row
    const float inv = 1.0f/1024.0f;
    float m1 = 0, m2 = 0;
    #pragma unroll
    for (int jl = 0; jl < 8; ++jl) {
        int k = (ch<<3) + jl + 1;
        run1 += p[jl]; run2 += sp[jl];
        float t1 = run1*inv, t2 = run2*inv;
        T1[k<<6] = t1;
        T2[k<<6] = t2;
        float c = shc[k], sa = shs[k], sa2 = shs2[k];
        m1 += sa*t1 + c*t2;
        m2 += (sa2*t1 + 2.0f*sa*t2)*t1 + c*t2*t2;
    }
    // reduce moments over chl within wave (xor over lane bits 3..5)
    m1 += __shfl_xor(m1,  8, 64); m2 += __shfl_xor(m2,  8, 64);
    m1 += __shfl_xor(m1, 16, 64); m2 += __shfl_xor(m2, 16, 64);
    m1 += __shfl_xor(m1, 32, 64); m2 += __shfl_xor(m2, 32, 64);
    __syncthreads();   // swp reuse
    if (chl == 0) { swp1[(wv<<3)+o] = m1; swp2[(wv<<3)+o] = m2; }
    __syncthreads();
    if (tid < 8) {
        float a1 = 0, a2 = 0;
        for (int w = 0; w < 16; ++w) { a1 += swp1[(w<<3)+tid]; a2 += swp2[(w<<3)+tid]; }
        atomicAdd(&ws[OFF_M + obase + tid], a1);
        atomicAdd(&ws[OFF_M + 64 + obase + tid], a2);
    }
}

// Final: A/D from moments inline; out[b,o,n]=A[o]*(a_n*T1[k_n,o]+T2[k_n,o])
// + D[o] + x[b,o,n]. Gather coalesced over o, transpose in LDS, store over n.
__global__ __launch_bounds__(256) void kFinal(
    const float* __restrict__ x, const float* __restrict__ Wb,
    const float* __restrict__ gamma, const float* __restrict__ beta,
    const float* __restrict__ ws, float* __restrict__ out)
{
    __shared__ float tile[64*65];
    __shared__ float sa[64];
    __shared__ int   sk[64];
    __shared__ float sA[64];
    __shared__ float sD[64];
    int tid = threadIdx.x;
    int b = blockIdx.x >> 6;
    int n0 = (blockIdx.x & 63) << 6;
    if (tid < 64) {
        sa[tid] = ws[OFF_A + (b<<12) + n0 + tid];
        sk[tid] = ((const int*)ws)[OFF_KK + (b<<12) + n0 + tid];
        const float Ninv = 1.0f/32768.0f;
        float m1 = ws[OFF_M + tid] * Ninv;
        float m2 = ws[OFF_M + 64 + tid] * Ninv;
        float wb = Wb[tid];
        float mu  = m1 + wb;
        float E2  = m2 + 2.0f*wb*m1 + wb*wb;
        float var = E2 - mu*mu;
        float A = gamma[tid] * rsqrtf(var + 1e-5f);
        sA[tid] = A;
        sD[tid] = beta[tid] + A*(wb - mu);
    }
    __syncthreads();
    const float* T1 = ws + OFF_T1 + b*65600;
    const float* T2 = ws + OFF_T2 + b*65600;
    {
        int o = tid & 63, ng = tid >> 6;
        float Ao = sA[o], Do = sD[o];
        for (int j = 0; j < 16; ++j) {
            int n = (ng << 4) + j;
            int k = sk[n];
            float a = sa[n];
            float t1 = T1[(k<<6) + o];
            float t2 = T2[(k<<6) + o];
            tile[o*65 + n] = Ao*(a*t1 + t2) + Do;
        }
    }
    __syncthreads();
    {
        int n = tid & 63, og = tid >> 6;
        for (int j = 0; j < 16; ++j) {
            int o = (og << 4) + j;
            int idx = ((b<<6) + o)*4096 + n0 + n;
            out[idx] = tile[o*65 + n] + x[idx];
        }
    }
}

extern "C" void kernel_launch(void* const* d_in, const int* in_sizes, int n_in,
                              void* d_out, int out_size, void* d_ws, size_t ws_size,
                              hipStream_t stream)
{
    const float* x       = (const float*)d_in[0];
    const float* theta_w = (const float*)d_in[1];
    const float* theta_b = (const float*)d_in[2];
    const float* phi_w   = (const float*)d_in[3];
    const float* phi_b   = (const float*)d_in[4];
    const float* psi_w   = (const float*)d_in[5];
    const float* psi_b   = (const float*)d_in[6];
    const float* cp_w    = (const float*)d_in[7];
    const float* Ww      = (const float*)d_in[8];
    const float* Wb      = (const float*)d_in[9];
    const float* gamma   = (const float*)d_in[10];
    const float* beta    = (const float*)d_in[11];
    float* ws  = (float*)d_ws;
    float* out = (float*)d_out;

    kA<<<1152, 256, 0, stream>>>(x, theta_w, theta_b, phi_w, phi_b,
                                 psi_w, psi_b, cp_w, Ww, ws);
    kRank<<<256, 256, 0, stream>>>(ws);
    kPS<<<64, 1024, 0, stream>>>(ws);
    kFinal<<<512, 256, 0, stream>>>(x, Wb, gamma, beta, ws, out);
}

// Round 6
// 132.080 us; speedup vs baseline: 1.2198x; 1.0063x over previous
//
#include <hip/hip_runtime.h>

// B=8, C=64, H=W=64, CI=32, N=4096 pixels, M=1024 pooled.
// y[b,n,:] = (a_n*S1[k_n,:] + S2[k_n,:])/1024 ; only W_w . y is needed, so
// track U = Ww.psi (64-dim) and its sorted-order prefixes T1/T2 directly.
// BN stats from per-k scalars (cnt, sum a, sum a^2) x T rows - no Gram.
// NOTE (r5 post-mortem): moments require the FULL-batch histogram per o;
// the og-sliced local-hist fusion is algebraically wrong. Keep hist global
// (computed in kRank over disjoint pixel slices, moments in kPS per-o).
#define OFF_A    0         // a[b][n]               : 32768 floats
#define OFF_BB   32768     // bb[b][m]              : 8192
#define OFF_SBB  40960     // sorted-desc bb[b][k]  : 8192
#define OFF_PERM 49152     // perm[b][k] (int)      : 8192
#define OFF_U    57344     // U[b][m][o]            : 8*1024*64 = 524288
#define OFF_T1   581632    // T1[b][k<=1024][o]     : 8*1025*64 = 524800
#define OFF_T2   1106432   // T2[b][k][o]           : 524800
#define OFF_KK   1631232   // k[b][n] (int)         : 32768
#define OFF_M    1664000   // M1[64], M2[64]        : 128
#define OFF_HC   1664128   // hist cnt[b][1025]     : 8200
#define OFF_HS   1672328   // hist sum_a[b][1025]   : 8200
#define OFF_HS2  1680528   // hist sum_a2[b][1025]  : 8200
// total 1688728 floats ~ 6.76 MB of d_ws

// Kernel A: blocks [0,1024): fused phi/psi 1x1-conv + 2x2 maxpool;
// bb = w2 . phi_pool (shuffle-reduced); U[m][o] = Ww[o,:] . psi_pool[m,:]
// via LDS transpose. Blocks [1024,1152): theta path collapsed:
// a[b,n] = x[b,:,n].tw_eff + tb_eff. Block 1024 zeros M + hist.
__global__ __launch_bounds__(256) void kA(
    const float* __restrict__ x, const float* __restrict__ theta_w,
    const float* __restrict__ theta_b, const float* __restrict__ phi_w,
    const float* __restrict__ phi_b, const float* __restrict__ psi_w,
    const float* __restrict__ psi_b, const float* __restrict__ cp_w,
    const float* __restrict__ Ww, float* ws)
{
    __shared__ float sm[4160];    // 32 i-rows x 130: interleaved {phi,psi}
    __shared__ float spsi[8*33];  // 8 m-rows x 32 i (padded)
    __shared__ float sWw[64*33];  // 64 o-rows x 32 i (padded)
    int tid = threadIdx.x;
    int bid = blockIdx.x;
    if (bid < 1024) {
        for (int e = tid; e < 2048; e += 256) {
            int i = e >> 6, c = e & 63;
            sm[i*130 + 2*c]     = phi_w[e];
            sm[i*130 + 2*c + 1] = psi_w[e];
        }
        for (int e = tid; e < 2048; e += 256)
            sWw[(e >> 5)*33 + (e & 31)] = Ww[(e >> 5)*33 + (e & 31)];
        __syncthreads();
        int t = (bid << 8) + tid;
        int i = t & 31;
        int m = (t >> 5) & 1023;
        int b = t >> 15;
        int ph = m >> 5, pw = m & 31;
        const float* xb = x + b*262144 + ph*128 + pw*2;
        // b64 LDS reads; lanes i and i+16 share a bank pair: free 2-way
        const float2* wrow = (const float2*)(sm + i*130);
        float p0=0,p1=0,p2=0,p3=0,s0=0,s1=0,s2=0,s3=0;
        #pragma unroll 8
        for (int c = 0; c < 64; ++c) {
            float2 xa = *(const float2*)(xb + c*4096);
            float2 xc = *(const float2*)(xb + c*4096 + 64);
            float2 w  = wrow[c];       // {phi_w, psi_w}
            p0 += xa.x*w.x; p1 += xa.y*w.x; p2 += xc.x*w.x; p3 += xc.y*w.x;
            s0 += xa.x*w.y; s1 += xa.y*w.y; s2 += xc.x*w.y; s3 += xc.y*w.y;
        }
        float pv = fmaxf(fmaxf(p0,p1), fmaxf(p2,p3)) + phi_b[i];
        float sv = fmaxf(fmaxf(s0,s1), fmaxf(s2,s3)) + psi_b[i];
        spsi[(tid >> 5)*33 + i] = sv;
        float v = pv * cp_w[32 + i];
        v += __shfl_xor(v, 16, 32);
        v += __shfl_xor(v,  8, 32);
        v += __shfl_xor(v,  4, 32);
        v += __shfl_xor(v,  2, 32);
        v += __shfl_xor(v,  1, 32);
        if (i == 0) ws[OFF_BB + (b<<10) + m] = v;
        __syncthreads();
        int m0 = (bid & 127) << 3;
        #pragma unroll
        for (int rep = 0; rep < 2; ++rep) {
            int idx = tid + (rep << 8);       // 512 outputs = 8 m x 64 o
            int ml = idx >> 6, o = idx & 63;
            const float* pr = &spsi[ml*33];   // wave-uniform ml: broadcast
            const float* wr = &sWw[o*33];     // (o+i)%32: 2-way max (free)
            float u = 0;
            #pragma unroll
            for (int i2 = 0; i2 < 32; ++i2) u += pr[i2]*wr[i2];
            ws[OFF_U + (((b<<10) + m0 + ml) << 6) + o] = u;
        }
    } else {
        if (bid == 1024) {   // zero M + hist (contiguous 128+24600 floats)
            for (int e = tid; e < 24728; e += 256) ws[OFF_M + e] = 0.0f;
        }
        if (tid < 64) {
            float s = 0;
            for (int i = 0; i < 32; ++i) s += cp_w[i]*theta_w[i*64 + tid];
            sm[tid] = s;
        } else if (tid == 64) {
            float s = 0;
            for (int i = 0; i < 32; ++i) s += cp_w[i]*theta_b[i];
            sm[64] = s;
        }
        __syncthreads();
        int t = ((bid - 1024) << 8) + tid;
        int n = t & 4095, b = t >> 12;
        const float* xb = x + b*262144 + n;
        float acc = sm[64];
        #pragma unroll 8
        for (int c = 0; c < 64; ++c) acc += xb[c*4096]*sm[c];
        ws[OFF_A + t] = acc;
    }
}

// kRank: (b, chunk) blocks. Part 1: rank 32 m's by counting (descending,
// index tiebreak), scatter sorted value + perm. Part 2: k_n for 128 pixels
// by direct count (k_n = #{m: bb_m > -a_n}) + FULL-batch histogram atomics.
__global__ __launch_bounds__(256) void kRank(float* ws)
{
    __shared__ float sb[1024];
    int tid = threadIdx.x;
    int b = blockIdx.x >> 5, chunk = blockIdx.x & 31;
    const float* bb = ws + OFF_BB + (b<<10);
    for (int e = tid; e < 1024; e += 256) sb[e] = bb[e];
    __syncthreads();
    {   // part 1: rank
        int ml = tid >> 3, jl = tid & 7;
        int m = (chunk<<5) + ml;
        float v = sb[m];
        int cnt = 0;
        for (int s = 0; s < 128; ++s) {
            int j = jl + (s<<3);
            float u = sb[j];
            cnt += (u > v || (u == v && j < m)) ? 1 : 0;
        }
        cnt += __shfl_xor(cnt, 1, 8);
        cnt += __shfl_xor(cnt, 2, 8);
        cnt += __shfl_xor(cnt, 4, 8);
        if (jl == 0) {
            ws[OFF_SBB + (b<<10) + cnt] = v;
            ((int*)ws)[OFF_PERM + (b<<10) + cnt] = m;
        }
    }
    {   // part 2: k_n + hist (2 threads per pixel, float2 LDS reads)
        int l = tid >> 1, jl = tid & 1;
        int n = (chunk<<7) + l;
        float av = ws[OFF_A + (b<<12) + n];
        float tt = -av;
        const float2* sb2 = (const float2*)sb;
        int cnt = 0;
        for (int s = 0; s < 256; ++s) {
            float2 u = sb2[jl + (s<<1)];   // 2 distinct addrs/wave: free
            cnt += (u.x > tt) ? 1 : 0;
            cnt += (u.y > tt) ? 1 : 0;
        }
        cnt += __shfl_xor(cnt, 1, 64);
        if (jl == 0) {
            ((int*)ws)[OFF_KK + (b<<12) + n] = cnt;
            atomicAdd(&ws[OFF_HC + b*1025 + cnt], 1.0f);
            atomicAdd(&ws[OFF_HS + b*1025 + cnt], av);
            atomicAdd(&ws[OFF_HS2 + b*1025 + cnt], av*av);
        }
    }
}

// kPS: (b, o-group of 8) blocks, 1024 threads = 128 chunks x 8 o.
// Register-cached gathers of U in sorted order, shuffle two-level scan ->
// T1/T2 prefixes; BN moment partials from FULL hist x T accumulated inline.
__global__ __launch_bounds__(1024) void kPS(float* ws)
{
    __shared__ float ssort[1024];
    __shared__ int   sperm[1024];
    __shared__ float shc[1025], shs[1025], shs2[1025];
    __shared__ float swp1[128], swp2[128];   // per-(wave,o) partials
    int tid = threadIdx.x;
    int b = blockIdx.x >> 3, og = blockIdx.x & 7;
    int obase = og << 3;
    ssort[tid] = ws[OFF_SBB + (b<<10) + tid];
    sperm[tid] = ((const int*)ws)[OFF_PERM + (b<<10) + tid];
    shc[tid]  = ws[OFF_HC  + b*1025 + tid];
    shs[tid]  = ws[OFF_HS  + b*1025 + tid];
    shs2[tid] = ws[OFF_HS2 + b*1025 + tid];
    if (tid == 0) {
        shc[1024]  = ws[OFF_HC  + b*1025 + 1024];
        shs[1024]  = ws[OFF_HS  + b*1025 + 1024];
        shs2[1024] = ws[OFF_HS2 + b*1025 + 1024];
    }
    __syncthreads();
    int ch = tid >> 3, o = tid & 7;
    int wv = tid >> 6, chl = (tid & 63) >> 3;   // ch = wv*8 + chl
    const float* Ub = ws + OFF_U + (b<<16) + obase + o;
    float p[8], sp[8];
    float s1 = 0, s2 = 0;
    #pragma unroll
    for (int jl = 0; jl < 8; ++jl) {
        int jj = (ch<<3) + jl;
        float v = Ub[sperm[jj]<<6];
        p[jl] = v;
        sp[jl] = ssort[jj]*v;
        s1 += v; s2 += sp[jl];
    }
    float own1 = s1, own2 = s2;
    // intra-wave inclusive scan over chl (8 chunks/wave)
    #pragma unroll
    for (int d = 1; d < 8; d <<= 1) {
        float u1 = __shfl_up(s1, d<<3, 64);
        float u2 = __shfl_up(s2, d<<3, 64);
        if (chl >= d) { s1 += u1; s2 += u2; }
    }
    if (chl == 7) { swp1[(wv<<3)+o] = s1; swp2[(wv<<3)+o] = s2; }
    __syncthreads();
    float off1 = 0, off2 = 0;
    for (int w = 0; w < 16; ++w) {
        if (w < wv) { off1 += swp1[(w<<3)+o]; off2 += swp2[(w<<3)+o]; }
    }
    float run1 = off1 + s1 - own1;   // exclusive prefix before chunk ch
    float run2 = off2 + s2 - own2;
    float* T1 = ws + OFF_T1 + b*65600 + obase + o;
    float* T2 = ws + OFF_T2 + b*65600 + obase + o;
    if (ch == 0) { T1[0] = 0.0f; T2[0] = 0.0f; }   // k=0 row
    const float inv = 1.0f/1024.0f;
    float m1 = 0, m2 = 0;
    #pragma unroll
    for (int jl = 0; jl < 8; ++jl) {
        int k = (ch<<3) + jl + 1;
        run1 += p[jl]; run2 += sp[jl];
        float t1 = run1*inv, t2 = run2*inv;
        T1[k<<6] = t1;
        T2[k<<6] = t2;
        float c = shc[k], sa = shs[k], sa2 = shs2[k];
        m1 += sa*t1 + c*t2;
        m2 += (sa2*t1 + 2.0f*sa*t2)*t1 + c*t2*t2;
    }
    // reduce moments over chl within wave (xor over lane bits 3..5)
    m1 += __shfl_xor(m1,  8, 64); m2 += __shfl_xor(m2,  8, 64);
    m1 += __shfl_xor(m1, 16, 64); m2 += __shfl_xor(m2, 16, 64);
    m1 += __shfl_xor(m1, 32, 64); m2 += __shfl_xor(m2, 32, 64);
    __syncthreads();   // swp reuse
    if (chl == 0) { swp1[(wv<<3)+o] = m1; swp2[(wv<<3)+o] = m2; }
    __syncthreads();
    if (tid < 8) {
        float a1 = 0, a2 = 0;
        for (int w = 0; w < 16; ++w) { a1 += swp1[(w<<3)+tid]; a2 += swp2[(w<<3)+tid]; }
        atomicAdd(&ws[OFF_M + obase + tid], a1);
        atomicAdd(&ws[OFF_M + 64 + obase + tid], a2);
    }
}

// Final: A/D from moments inline; out[b,o,n]=A[o]*(a_n*T1[k_n,o]+T2[k_n,o])
// + D[o] + x[b,o,n]. Gather coalesced over o, transpose in LDS, store over n.
__global__ __launch_bounds__(256) void kFinal(
    const float* __restrict__ x, const float* __restrict__ Wb,
    const float* __restrict__ gamma, const float* __restrict__ beta,
    const float* __restrict__ ws, float* __restrict__ out)
{
    __shared__ float tile[64*65];
    __shared__ float sa[64];
    __shared__ int   sk[64];
    __shared__ float sA[64];
    __shared__ float sD[64];
    int tid = threadIdx.x;
    int b = blockIdx.x >> 6;
    int n0 = (blockIdx.x & 63) << 6;
    if (tid < 64) {
        sa[tid] = ws[OFF_A + (b<<12) + n0 + tid];
        sk[tid] = ((const int*)ws)[OFF_KK + (b<<12) + n0 + tid];
        const float Ninv = 1.0f/32768.0f;
        float m1 = ws[OFF_M + tid] * Ninv;
        float m2 = ws[OFF_M + 64 + tid] * Ninv;
        float wb = Wb[tid];
        float mu  = m1 + wb;
        float E2  = m2 + 2.0f*wb*m1 + wb*wb;
        float var = E2 - mu*mu;
        float A = gamma[tid] * rsqrtf(var + 1e-5f);
        sA[tid] = A;
        sD[tid] = beta[tid] + A*(wb - mu);
    }
    __syncthreads();
    const float* T1 = ws + OFF_T1 + b*65600;
    const float* T2 = ws + OFF_T2 + b*65600;
    {
        int o = tid & 63, ng = tid >> 6;
        float Ao = sA[o], Do = sD[o];
        for (int j = 0; j < 16; ++j) {
            int n = (ng << 4) + j;
            int k = sk[n];
            float a = sa[n];
            float t1 = T1[(k<<6) + o];
            float t2 = T2[(k<<6) + o];
            tile[o*65 + n] = Ao*(a*t1 + t2) + Do;
        }
    }
    __syncthreads();
    {
        int n = tid & 63, og = tid >> 6;
        for (int j = 0; j < 16; ++j) {
            int o = (og << 4) + j;
            int idx = ((b<<6) + o)*4096 + n0 + n;
            out[idx] = tile[o*65 + n] + x[idx];
        }
    }
}

extern "C" void kernel_launch(void* const* d_in, const int* in_sizes, int n_in,
                              void* d_out, int out_size, void* d_ws, size_t ws_size,
                              hipStream_t stream)
{
    const float* x       = (const float*)d_in[0];
    const float* theta_w = (const float*)d_in[1];
    const float* theta_b = (const float*)d_in[2];
    const float* phi_w   = (const float*)d_in[3];
    const float* phi_b   = (const float*)d_in[4];
    const float* psi_w   = (const float*)d_in[5];
    const float* psi_b   = (const float*)d_in[6];
    const float* cp_w    = (const float*)d_in[7];
    const float* Ww      = (const float*)d_in[8];
    const float* Wb      = (const float*)d_in[9];
    const float* gamma   = (const float*)d_in[10];
    const float* beta    = (const float*)d_in[11];
    float* ws  = (float*)d_ws;
    float* out = (float*)d_out;

    kA<<<1152, 256, 0, stream>>>(x, theta_w, theta_b, phi_w, phi_b,
                                 psi_w, psi_b, cp_w, Ww, ws);
    kRank<<<256, 256, 0, stream>>>(ws);
    kPS<<<64, 1024, 0, stream>>>(ws);
    kFinal<<<512, 256, 0, stream>>>(x, Wb, gamma, beta, ws, out);
}